// Round 17
// baseline (351.591 us; speedup 1.0000x reference)
//
#include <hip/hip_runtime.h>
#include <stdint.h>

#define B_SZ 4096
#define D_K  2048   // D_IN + D_H
#define DH   1024

#define BM   128    // M rows per block
#define BN_H 32     // h columns per block (x4 gates = 128 N columns)
#define BK   64     // bf16 K elements per LDS tile (128 B rows — byte-identical
                    // to the verified i8 BKI=128 layout)
#define NIT  (D_K / BK)   // 32 K-iterations

typedef __attribute__((ext_vector_type(8))) short bf16x8;
typedef __attribute__((ext_vector_type(4))) float f32x4;
typedef __attribute__((ext_vector_type(4))) unsigned short us4;

__device__ __forceinline__ float fast_sigmoid(float x) {
  return 1.0f / (1.0f + __expf(-x));
}
__device__ __forceinline__ float fast_tanh(float x) {
  return 2.0f / (1.0f + __expf(-2.0f * x)) - 1.0f;
}

// fp32 -> bf16 RTNE (bit trick; inputs are finite)
__device__ __forceinline__ unsigned short bf16r(float f) {
  uint32_t u = __float_as_uint(f);
  return (unsigned short)((u + 0x7FFFu + ((u >> 16) & 1u)) >> 16);
}
__device__ __forceinline__ us4 cvt4(float4 v) {
  us4 o;
  o.x = bf16r(v.x); o.y = bf16r(v.y); o.z = bf16r(v.z); o.w = bf16r(v.w);
  return o;
}

// ============================================================================
// SINGLE-PASS bf16 GEMM + LSTM epilogue. Replaces the two-pass i8 design:
// R12/R15 proved the quant pass + grid sync costs ~100-120us while the GEMM
// is latency-bound (MFMA busy only ~14us) — so we spend MFMA headroom (bf16 =
// 2x i8 insts) to delete the entire first pass.
//
//  * Geometry = R0's verified tiling: 128M x (4g x 32h), 4 waves 2Mx2N,
//    wave tile 64x64 = 4x4 frags of 16x16x32_bf16, fp32 accumulation.
//  * LDS 32 KB (16KB A + 16KB B), single-buffered, 3 blocks/CU.
//  * Staging: reg-staged fp32 loads (4 rows x 256B per instr, coalesced),
//    in-register cvt to bf16, ds_write_b64 with the SAME chunk-XOR swizzle
//    as the verified i8 kernel: row r's logical 16B chunk c at physical
//    c^(r&7). Reg-staging writes the swizzle directly (both sides consistent).
//    LDS rows are 128 B (64 bf16) — byte-identical addressing to i8 BKI=128,
//    so fragment reads (cx0/cx1) and the C/D-layout epilogue carry over
//    verbatim. K-tiles 0..15 come from xin, 16..31 from hprev (BK=64 divides
//    the 1024 split exactly).
//  * XCD-chunked block swizzle: XCD j (bid%8 heuristic) gets contiguous
//    orig ids [j*128, j*128+128) = bx in [4j, 4j+4) — its 4 A-panels (4MB)
//    stay L2-resident, cutting the fp32 re-read traffic. Wrong mapping only
//    costs speed, never correctness.
//  * No workspace, no second kernel, no grid sync, no scales.
// ============================================================================
__global__ __launch_bounds__(256, 3) void lstm_bf16(
    const float* __restrict__ xin, const float* __restrict__ hprev,
    const float* __restrict__ Wi, const float* __restrict__ Wf,
    const float* __restrict__ Wc, const float* __restrict__ Wo,
    const float* __restrict__ bi, const float* __restrict__ bfv,
    const float* __restrict__ bc, const float* __restrict__ bo,
    const float* __restrict__ cprev, float* __restrict__ out)
{
  __shared__ __align__(16) int8_t lA[BM * BK * 2];   // 16 KB (bytes)
  __shared__ __align__(16) int8_t lB[128 * BK * 2];  // 16 KB

  const int tid = threadIdx.x;
  const int wave = tid >> 6;
  const int lane = tid & 63;

  // ---- XCD-chunked grid swizzle (bijective: 1024 % 8 == 0)
  const int bid  = blockIdx.y * gridDim.x + blockIdx.x;   // 0..1023
  const int orig = (bid & 7) * 128 + (bid >> 3);
  const int m0 = (orig >> 5) * BM;    // bx in [4*xcd, 4*xcd+4)
  const int h0 = (orig & 31) * BN_H;

  // ---- staging geometry: round j (0..7) covers rows [j*16, j*16+16).
  // thread: row r = j*16 + sr, col-quad sc (4 fp32 = 16B load -> 8B bf16).
  const int sr = tid >> 4;   // 0..15
  const int sc = tid & 15;   // 0..15
  // LDS byte addr: r*128 + ((sc>>1)^(r&7))*16 + (sc&1)*8 ; r&7 == sr&7.
  const int ldsOff = sr * 128 + (((sc >> 1) ^ (sr & 7)) << 4) + ((sc & 1) << 3);

  // A row base pointers (x and h halves), advanced by kt*64 in the loop.
  const float* aX = xin   + (size_t)(m0 + sr) * 1024 + sc * 4;
  const float* aH = hprev + (size_t)(m0 + sr) * 1024 + sc * 4;
  // B (W) row pointers: LDS row r -> gate j>>1, h = h0 + (j&1)*16 + sr.
  const float* gw[4] = {Wi, Wf, Wc, Wo};
  const float* wB[8];
  #pragma unroll
  for (int j = 0; j < 8; ++j)
    wB[j] = gw[j >> 1] + (size_t)(h0 + (j & 1) * 16 + sr) * D_K + sc * 4;

  f32x4 acc[4][4];
  #pragma unroll
  for (int i = 0; i < 4; ++i)
    #pragma unroll
    for (int j = 0; j < 4; ++j)
      acc[i][j] = (f32x4){0.f, 0.f, 0.f, 0.f};

  // ---- fragment reads: VERBATIM from the verified i8 kernel (byte-level).
  const int wm = wave >> 1;   // M half (64 rows)
  const int wn = wave & 1;    // h half (16 cols)
  const int fr = lane & 15;
  const int q  = lane >> 4;
  const int cx0 = ((q + 0) ^ (fr & 7)) * 16;   // kk=0
  const int cx1 = ((q + 4) ^ (fr & 7)) * 16;   // kk=1

  #pragma unroll 1
  for (int kt = 0; kt < NIT; ++kt) {
    // ---- stage: 8 A loads + 8 W loads (fp32), cvt, swizzled ds_write
    const float* ap = (kt < 16) ? (aX + kt * BK) : (aH + (kt - 16) * BK);
    const int wo = kt * BK;
    #pragma unroll
    for (int j = 0; j < 8; ++j) {
      float4 av = *(const float4*)(ap + (size_t)j * 16 * 1024);
      float4 wv = *(const float4*)(wB[j] + wo);
      *(us4*)&lA[ldsOff + j * 2048] = cvt4(av);
      *(us4*)&lB[ldsOff + j * 2048] = cvt4(wv);
    }
    __syncthreads();

    // ---- compute: 2 kk x 16 MFMA (16x16x32 bf16)
    #pragma unroll
    for (int kk = 0; kk < 2; ++kk) {
      const int cx = kk ? cx1 : cx0;
      bf16x8 bq[4];
      #pragma unroll
      for (int g = 0; g < 4; ++g)
        bq[g] = *(const bf16x8*)&lB[(g * 32 + wn * 16 + fr) * 128 + cx];
      #pragma unroll
      for (int i = 0; i < 4; ++i) {
        bf16x8 aq = *(const bf16x8*)&lA[(wm * 64 + i * 16 + fr) * 128 + cx];
        acc[i][0] = __builtin_amdgcn_mfma_f32_16x16x32_bf16(aq, bq[0], acc[i][0], 0, 0, 0);
        acc[i][1] = __builtin_amdgcn_mfma_f32_16x16x32_bf16(aq, bq[1], acc[i][1], 0, 0, 0);
        acc[i][2] = __builtin_amdgcn_mfma_f32_16x16x32_bf16(aq, bq[2], acc[i][2], 0, 0, 0);
        acc[i][3] = __builtin_amdgcn_mfma_f32_16x16x32_bf16(aq, bq[3], acc[i][3], 0, 0, 0);
      }
    }
    __syncthreads();
  }

  // ---- epilogue: C/D layout col=lane&15, row=(lane>>4)*4+reg
  // (dtype-independent — identical mapping to the verified i8 kernel).
  // acc IS z (no scales): z = acc + bias.
  const int col = lane & 15;
  const int rq = lane >> 4;
  const int h = h0 + wn * 16 + col;
  const float bias_i = bi[h], bias_f = bfv[h], bias_c = bc[h], bias_o = bo[h];
  float* hout = out;
  float* cout = out + (size_t)B_SZ * DH;
  #pragma unroll
  for (int i = 0; i < 4; ++i) {
    int mb = m0 + wm * 64 + i * 16 + rq * 4;
    #pragma unroll
    for (int r = 0; r < 4; ++r) {
      int m = mb + r;
      float zi = acc[i][0][r] + bias_i;
      float zf = acc[i][1][r] + bias_f;
      float zc = acc[i][2][r] + bias_c;
      float zo = acc[i][3][r] + bias_o;
      float ig = fast_sigmoid(zi);
      float fg = fast_sigmoid(zf);
      float cg = fast_tanh(zc);
      float og = fast_sigmoid(zo);
      float cp = cprev[(size_t)m * DH + h];
      float cn = fg * cp + ig * cg;
      float hn = og * fast_tanh(cn);
      hout[(size_t)m * DH + h] = hn;
      cout[(size_t)m * DH + h] = cn;
    }
  }
}

extern "C" void kernel_launch(void* const* d_in, const int* in_sizes, int n_in,
                              void* d_out, int out_size, void* d_ws, size_t ws_size,
                              hipStream_t stream)
{
  const float* xin   = (const float*)d_in[0];
  const float* hprev = (const float*)d_in[1];
  const float* cprev = (const float*)d_in[2];
  const float* Wi    = (const float*)d_in[3];
  const float* bi    = (const float*)d_in[4];
  const float* Wf    = (const float*)d_in[5];
  const float* bfv   = (const float*)d_in[6];
  const float* Wc    = (const float*)d_in[7];
  const float* bc    = (const float*)d_in[8];
  const float* Wo    = (const float*)d_in[9];
  const float* bo    = (const float*)d_in[10];
  float* out = (float*)d_out;

  dim3 grid(B_SZ / BM, DH / BN_H);  // 32 x 32 = 1024 blocks
  lstm_bf16<<<grid, 256, 0, stream>>>(
      xin, hprev, Wi, Wf, Wc, Wo, bi, bfv, bc, bo, cprev, out);
}